// Round 1
// baseline (304025.317 us; speedup 1.0000x reference)
//
#include <hip/hip_runtime.h>
#include <hip/hip_cooperative_groups.h>
#include <cstddef>

namespace cg = cooperative_groups;

#define BB 32
#define TT 4096
#define PP 512
#define WW 1024

constexpr int NWG  = 256;   // one workgroup per CU
constexpr int NTHR = 768;   // 12 waves

// h buffer layout: element index (k>>2)*BB*4 + b*4 + (k&3)  (float4 index: (k>>2)*BB + b)
// so a wave reading fixed k4, b=0..31 as float4 touches 512B contiguous.

__global__ __launch_bounds__(NTHR, 3) void gru_scan_kernel(
    const float* __restrict__ a,        // [B,T,P]
    const float* __restrict__ h0,       // [W]
    const float* __restrict__ Wih,      // [3W,P]
    const float* __restrict__ Whh,      // [3W,W]
    const float* __restrict__ bias,     // [3W]
    const float* __restrict__ bias_n,   // [W]
    const float* __restrict__ Wout,     // [P,W]
    const float* __restrict__ bout,     // [P]
    float* __restrict__ out,            // [B,T,P]
    float* __restrict__ hbufA,          // [W*B] in packed layout
    float* __restrict__ hbufB)
{
    __shared__ float sWhh[12][WW];          // 48 KB: this WG's 12 rows (3 gates x 4 w)
    __shared__ float sPreI[2][12][BB];      // ih-dot partials (+bias), per K-half
    __shared__ float sPreH[2][12][BB];      // hh-dot partials, per K-half
    __shared__ float sOutPart[12][64];      // out-projection K-partials

    const int g   = blockIdx.x;             // 0..255
    const int tid = threadIdx.x;            // 0..767
    const int w0  = g * 4;                  // this WG's hidden slice base

    // ---- load Whh slice into LDS (rows: gate*W + w0 + wi) ----
    for (int i = tid; i < 12 * (WW / 4); i += NTHR) {
        int row  = i / (WW / 4);
        int k4   = i - row * (WW / 4);
        int grow = (row >> 2) * WW + w0 + (row & 3);
        *(float4*)&sWhh[row][k4 * 4] = *(const float4*)&Whh[(size_t)grow * WW + k4 * 4];
    }

    // ---- init h buffer A with h0 broadcast (own slice only) ----
    if (tid < 128) {
        int wi = tid >> 5, b = tid & 31;
        hbufA[g * 128 + b * 4 + wi] = h0[w0 + wi];
    }

    // ---- per-thread constants ----
    // P1 mapping: 384 outputs (12 rows x 32 batches), two K-halves
    const int  half = (tid >= 384) ? 1 : 0;
    const int  sub  = tid - half * 384;
    const int  b1   = sub & 31;
    const int  row  = sub >> 5;                              // 0..11
    const int  grow = (row >> 2) * WW + w0 + (row & 3);
    const float biasv = (half == 0) ? bias[grow] : 0.0f;

    // P2 constants (threads 0..127: wi = tid>>5, b = tid&31)
    const float bnv = (tid < 128) ? bias_n[w0 + (tid >> 5)] : 0.0f;

    // P3 mapping: WG owns p0..p0+15 (full 64B lines) x 4 batches; 12 K-chunks
    const int  p0   = (g & 31) * 16;
    const int  b0   = (g >> 5) * 4;
    const int  o    = tid & 63;
    const int  c    = tid >> 6;                              // 0..11
    const int  p3p  = p0 + (o & 15);
    const int  p3b  = b0 + (o >> 4);
    const float boutv = (tid < 64) ? bout[p3p] : 0.0f;

    cg::grid_group grid = cg::this_grid();
    grid.sync();   // weights + h0 init visible everywhere

    const float* hcur = hbufA;
    float*       hnxt = hbufB;

    for (int t = TT - 1; t >= 0; --t) {
        // ---------- P1: gate pre-activation dots ----------
        float acc_h = 0.f, acc_i = biasv;
        {
            const int k40 = half * 128;                       // float4 base over K=1024
            const float4* __restrict__ h4 = (const float4*)hcur;
            #pragma unroll 8
            for (int k4 = 0; k4 < 128; ++k4) {
                float4 wv = *(const float4*)&sWhh[row][(k40 + k4) * 4];
                float4 hv = h4[(k40 + k4) * BB + b1];
                acc_h += wv.x * hv.x + wv.y * hv.y + wv.z * hv.z + wv.w * hv.w;
            }
            const float4* __restrict__ arow = (const float4*)&a[((size_t)b1 * TT + t) * PP];
            const float4* __restrict__ wrow = (const float4*)&Wih[(size_t)grow * PP];
            const int p40 = half * 64;                        // float4 base over P=512
            #pragma unroll 8
            for (int p4 = 0; p4 < 64; ++p4) {
                float4 av = arow[p40 + p4];
                float4 wv = wrow[p40 + p4];
                acc_i += av.x * wv.x + av.y * wv.y + av.z * wv.z + av.w * wv.w;
            }
        }
        sPreH[half][row][b1] = acc_h;
        sPreI[half][row][b1] = acc_i;
        __syncthreads();

        // ---------- P2: gates + h update (own 4 w's) ----------
        if (tid < 128) {
            int wi = tid >> 5, b = tid & 31;
            float ir  = sPreI[0][wi][b]     + sPreI[1][wi][b];
            float hr  = sPreH[0][wi][b]     + sPreH[1][wi][b];
            float iz  = sPreI[0][4 + wi][b] + sPreI[1][4 + wi][b];
            float hz  = sPreH[0][4 + wi][b] + sPreH[1][4 + wi][b];
            float inn = sPreI[0][8 + wi][b] + sPreI[1][8 + wi][b];
            float hnn = sPreH[0][8 + wi][b] + sPreH[1][8 + wi][b];
            float r = 1.f / (1.f + __expf(-(ir + hr)));
            float z = 1.f / (1.f + __expf(-(iz + hz)));
            float n = tanhf(inn + r * (hnn + bnv));
            int idx = g * 128 + b * 4 + wi;
            float hp = hcur[idx];
            hnxt[idx] = n + z * (hp - n);
        }
        grid.sync();   // h_t complete and visible

        // ---------- P3: output projection for time t ----------
        {
            const float4* __restrict__ h4   = (const float4*)hnxt;
            const float4* __restrict__ wrow = (const float4*)&Wout[(size_t)p3p * WW];
            float acc = 0.f;
            for (int k4 = c; k4 < WW / 4; k4 += 12) {
                float4 hv = h4[k4 * BB + p3b];
                float4 wv = wrow[k4];
                acc += hv.x * wv.x + hv.y * wv.y + hv.z * wv.z + hv.w * wv.w;
            }
            sOutPart[c][o] = acc;
        }
        __syncthreads();
        if (tid < 64) {
            float s_ = boutv;
            #pragma unroll
            for (int cc = 0; cc < 12; ++cc) s_ += sOutPart[cc][o];
            out[((size_t)p3b * TT + t) * PP + p3p] = s_;
        }

        // swap h buffers
        float* tmp = (float*)hcur; hcur = hnxt; hnxt = tmp;
    }
}

extern "C" void kernel_launch(void* const* d_in, const int* in_sizes, int n_in,
                              void* d_out, int out_size, void* d_ws, size_t ws_size,
                              hipStream_t stream) {
    const float* a      = (const float*)d_in[0];
    const float* h0     = (const float*)d_in[1];
    const float* Wih    = (const float*)d_in[2];
    const float* Whh    = (const float*)d_in[3];
    const float* bias   = (const float*)d_in[4];
    const float* bias_n = (const float*)d_in[5];
    const float* Wout   = (const float*)d_in[6];
    const float* bout   = (const float*)d_in[7];
    float* out = (float*)d_out;

    float* hA = (float*)d_ws;            // 32768 floats
    float* hB = hA + (size_t)WW * BB;    // 32768 floats

    void* args[] = {(void*)&a, (void*)&h0, (void*)&Wih, (void*)&Whh,
                    (void*)&bias, (void*)&bias_n, (void*)&Wout, (void*)&bout,
                    (void*)&out, (void*)&hA, (void*)&hB};
    hipLaunchCooperativeKernel((void*)gru_scan_kernel, dim3(NWG), dim3(NTHR),
                               args, 0, stream);
}

// Round 2
// 245431.543 us; speedup vs baseline: 1.2387x; 1.2387x over previous
//
#include <hip/hip_runtime.h>
#include <cstddef>

#define BB 32
#define TT 4096
#define PP 512
#define WW 1024

constexpr int NWG  = 256;   // one workgroup per CU
constexpr int NTHR = 768;   // 12 waves

// h buffer layout: float index (k>>2)*BB*4 + b*4 + (k&3)  (float4 index: (k>>2)*BB + b)

__device__ inline void lite_barrier(unsigned* ctr, unsigned target) {
    __syncthreads();
    if (threadIdx.x == 0) {
        __builtin_amdgcn_fence(__ATOMIC_RELEASE, "agent");
        __hip_atomic_fetch_add(ctr, 1u, __ATOMIC_RELAXED, __HIP_MEMORY_SCOPE_AGENT);
        while (__hip_atomic_load(ctr, __ATOMIC_RELAXED, __HIP_MEMORY_SCOPE_AGENT) < target)
            __builtin_amdgcn_s_sleep(1);
        __builtin_amdgcn_fence(__ATOMIC_ACQUIRE, "agent");
    }
    __syncthreads();
}

__global__ __launch_bounds__(NTHR, 3) void gru_scan_kernel(
    const float* __restrict__ a,        // [B,T,P]
    const float* __restrict__ h0,       // [W]
    const float* __restrict__ Wih,      // [3W,P]
    const float* __restrict__ Whh,      // [3W,W]
    const float* __restrict__ bias,     // [3W]
    const float* __restrict__ bias_n,   // [W]
    const float* __restrict__ Wout,     // [P,W]
    const float* __restrict__ bout,     // [P]
    float* __restrict__ out,            // [B,T,P]
    float* __restrict__ hbufA,
    float* __restrict__ hbufB,
    unsigned* __restrict__ bar_ctr)
{
    __shared__ float sWhh[12][WW];          // 48 KB
    __shared__ float sPreH[2][12][BB];
    __shared__ float sIg[2][12][BB];
    __shared__ float sOutPart[12][64];

    const int g   = blockIdx.x;
    const int tid = threadIdx.x;
    const int w0  = g * 4;

    // ---- load Whh slice into LDS ----
    for (int i = tid; i < 12 * (WW / 4); i += NTHR) {
        int row  = i / (WW / 4);
        int k4   = i - row * (WW / 4);
        int grow = (row >> 2) * WW + w0 + (row & 3);
        *(float4*)&sWhh[row][k4 * 4] = *(const float4*)&Whh[(size_t)grow * WW + k4 * 4];
    }

    // ---- init h buffer A with h0 broadcast (own slice) ----
    if (tid < 128) {
        int wi = tid >> 5, b = tid & 31;
        hbufA[g * 128 + b * 4 + wi] = h0[w0 + wi];
    }

    // ---- P1 mapping: 384 outputs (12 rows x 32 b), two K-halves ----
    const int  half = (tid >= 384) ? 1 : 0;
    const int  sub  = tid - half * 384;
    const int  b1   = sub & 31;
    const int  row  = sub >> 5;
    const int  grow = (row >> 2) * WW + w0 + (row & 3);
    const float biasv = (half == 0) ? bias[grow] : 0.0f;

    // ---- P2 constants + h_own register ----
    const float bnv   = (tid < 128) ? bias_n[w0 + (tid >> 5)] : 0.0f;
    float       h_own = (tid < 128) ? h0[w0 + (tid >> 5)] : 0.0f;

    // ---- P3 mapping ----
    const int  p0   = (g & 31) * 16;
    const int  b0   = (g >> 5) * 4;
    const int  o    = tid & 63;
    const int  c    = tid >> 6;
    const int  p3p  = p0 + (o & 15);
    const int  p3b  = b0 + (o >> 4);
    const float boutv = bout[p3p];

    // ih-dot for a given t -> sIg (reads only a/Wih, no h dependency)
    auto ihdot = [&](int t) {
        const float4* __restrict__ arow = (const float4*)&a[((size_t)b1 * TT + t) * PP];
        const float4* __restrict__ wrow = (const float4*)&Wih[(size_t)grow * PP];
        const int p40 = half * 64;
        float4 acc = {0.f, 0.f, 0.f, 0.f};
        #pragma unroll 8
        for (int p4 = 0; p4 < 64; ++p4) {
            float4 av = arow[p40 + p4];
            float4 wv = wrow[p40 + p4];
            acc.x += av.x * wv.x; acc.y += av.y * wv.y;
            acc.z += av.z * wv.z; acc.w += av.w * wv.w;
        }
        sIg[half][row][b1] = (acc.x + acc.y) + (acc.z + acc.w) + biasv;
    };

    // prologue: ih-dot for the first (reverse) step
    ihdot(TT - 1);

    unsigned bar_target = NWG;
    lite_barrier(bar_ctr, bar_target);   // h0-init + sWhh + sIg visible

    const float* hcur = hbufA;
    float*       hnxt = hbufB;

    for (int t = TT - 1; t >= 0; --t) {
        // ---------- A: hh-dot (critical path) ----------
        {
            const float4* __restrict__ h4 = (const float4*)hcur;
            const int k40 = half * 128;
            float4 acc = {0.f, 0.f, 0.f, 0.f};
            #pragma unroll 8
            for (int k4 = 0; k4 < 128; ++k4) {
                float4 wv = *(const float4*)&sWhh[row][(k40 + k4) * 4];
                float4 hv = h4[(k40 + k4) * BB + b1];
                acc.x += wv.x * hv.x; acc.y += wv.y * hv.y;
                acc.z += wv.z * hv.z; acc.w += wv.w * hv.w;
            }
            sPreH[half][row][b1] = (acc.x + acc.y) + (acc.z + acc.w);
        }

        // ---------- B: P3 partials for h_{t+1} (reads hcur too) ----------
        if (t < TT - 1) {
            const float4* __restrict__ h4   = (const float4*)hcur;
            const float4* __restrict__ wrow = (const float4*)&Wout[(size_t)p3p * WW];
            float4 acc = {0.f, 0.f, 0.f, 0.f};
            for (int k4 = c; k4 < WW / 4; k4 += 12) {
                float4 hv = h4[k4 * BB + p3b];
                float4 wv = wrow[k4];
                acc.x += hv.x * wv.x; acc.y += hv.y * wv.y;
                acc.z += hv.z * wv.z; acc.w += hv.w * wv.w;
            }
            sOutPart[c][o] = (acc.x + acc.y) + (acc.z + acc.w);
        }
        __syncthreads();

        // ---------- C: gates + h update ----------
        if (tid < 128) {
            int wi = tid >> 5, b = tid & 31;
            float ir  = sIg[0][wi][b]       + sIg[1][wi][b];
            float hr  = sPreH[0][wi][b]     + sPreH[1][wi][b];
            float iz  = sIg[0][4 + wi][b]   + sIg[1][4 + wi][b];
            float hz  = sPreH[0][4 + wi][b] + sPreH[1][4 + wi][b];
            float inn = sIg[0][8 + wi][b]   + sIg[1][8 + wi][b];
            float hnn = sPreH[0][8 + wi][b] + sPreH[1][8 + wi][b];
            float r = 1.f / (1.f + __expf(-(ir + hr)));
            float z = 1.f / (1.f + __expf(-(iz + hz)));
            float n = tanhf(inn + r * (hnn + bnv));
            float hnew = n + z * (h_own - n);
            h_own = hnew;
            hnxt[g * 128 + b * 4 + wi] = hnew;
        }

        // ---------- D: P3 reduce -> out[t+1] ----------
        if (t < TT - 1 && tid < 64) {
            float s_ = boutv;
            #pragma unroll
            for (int cc = 0; cc < 12; ++cc) s_ += sOutPart[cc][o];
            out[((size_t)p3b * TT + (t + 1)) * PP + p3p] = s_;
        }
        __syncthreads();   // C done reading sIg/sPreH before E overwrites

        // ---------- E: ih-dot for next step (hides a-stream latency) ----------
        if (t > 0) ihdot(t - 1);

        bar_target += NWG;
        lite_barrier(bar_ctr, bar_target);

        const float* tmp = hcur; hcur = hnxt; hnxt = (float*)tmp;
    }

    // ---------- epilogue: projection for h_0 -> out[0] ----------
    {
        const float4* __restrict__ h4   = (const float4*)hcur;
        const float4* __restrict__ wrow = (const float4*)&Wout[(size_t)p3p * WW];
        float4 acc = {0.f, 0.f, 0.f, 0.f};
        for (int k4 = c; k4 < WW / 4; k4 += 12) {
            float4 hv = h4[k4 * BB + p3b];
            float4 wv = wrow[k4];
            acc.x += hv.x * wv.x; acc.y += hv.y * wv.y;
            acc.z += hv.z * wv.z; acc.w += hv.w * wv.w;
        }
        sOutPart[c][o] = (acc.x + acc.y) + (acc.z + acc.w);
    }
    __syncthreads();
    if (tid < 64) {
        float s_ = boutv;
        #pragma unroll
        for (int cc = 0; cc < 12; ++cc) s_ += sOutPart[cc][o];
        out[((size_t)p3b * TT + 0) * PP + p3p] = s_;
    }
}

extern "C" void kernel_launch(void* const* d_in, const int* in_sizes, int n_in,
                              void* d_out, int out_size, void* d_ws, size_t ws_size,
                              hipStream_t stream) {
    const float* a      = (const float*)d_in[0];
    const float* h0     = (const float*)d_in[1];
    const float* Wih    = (const float*)d_in[2];
    const float* Whh    = (const float*)d_in[3];
    const float* bias   = (const float*)d_in[4];
    const float* bias_n = (const float*)d_in[5];
    const float* Wout   = (const float*)d_in[6];
    const float* bout   = (const float*)d_in[7];
    float* out = (float*)d_out;

    float*    hA  = (float*)d_ws;                       // 32768 floats
    float*    hB  = hA + (size_t)WW * BB;               // 32768 floats
    unsigned* ctr = (unsigned*)((char*)d_ws + 2 * (size_t)WW * BB * sizeof(float));

    // reset the barrier counter every launch (graph-capture safe)
    hipMemsetAsync(ctr, 0, 128, stream);

    void* args[] = {(void*)&a, (void*)&h0, (void*)&Wih, (void*)&Whh,
                    (void*)&bias, (void*)&bias_n, (void*)&Wout, (void*)&bout,
                    (void*)&out, (void*)&hA, (void*)&hB, (void*)&ctr};
    hipLaunchCooperativeKernel((void*)gru_scan_kernel, dim3(NWG), dim3(NTHR),
                               args, 0, stream);
}

// Round 3
// 179422.375 us; speedup vs baseline: 1.6945x; 1.3679x over previous
//
#include <hip/hip_runtime.h>
#include <cstddef>

#define BB 32
#define TT 4096
#define PP 512
#define WW 1024

constexpr int NWG  = 256;   // one workgroup per CU
constexpr int NTHR = 768;   // 12 waves

using u32 = unsigned;
using u64 = unsigned long long;

// round-to-nearest-even f32 -> bf16 (as u16 in low bits)
__device__ __forceinline__ u32 bfround(float f) {
    u32 u = __float_as_uint(f);
    return (u + 0x7fffu + ((u >> 16) & 1u)) >> 16;
}

// Grid barrier with NO cache-maintenance ops: h traffic is all agent-scope
// (L2-bypassing) atomics, so visibility needs only vmcnt drain + L3 atomics.
__device__ __forceinline__ void grid_barrier(u32* leaf, u32* root, u32 rtarget, int g) {
    asm volatile("s_waitcnt vmcnt(0)" ::: "memory");
    __syncthreads();
    if (threadIdx.x == 0) {
        u32 old = __hip_atomic_fetch_add(&leaf[(g & 7) * 16], 1u,
                                         __ATOMIC_RELAXED, __HIP_MEMORY_SCOPE_AGENT);
        if ((old & 31u) == 31u)   // last of this leaf's 32 WGs this step
            __hip_atomic_fetch_add(root, 1u, __ATOMIC_RELAXED, __HIP_MEMORY_SCOPE_AGENT);
        while (__hip_atomic_load(root, __ATOMIC_RELAXED, __HIP_MEMORY_SCOPE_AGENT) < rtarget)
            __builtin_amdgcn_s_sleep(2);
    }
    __syncthreads();
}

__global__ __launch_bounds__(NTHR, 1) void gru_scan_kernel(
    const float* __restrict__ a,        // [B,T,P]
    const float* __restrict__ h0,       // [W]
    const float* __restrict__ Wih,      // [3W,P]
    const float* __restrict__ Whh,      // [3W,W]
    const float* __restrict__ bias,     // [3W]
    const float* __restrict__ bias_n,   // [W]
    const float* __restrict__ Wout,     // [P,W]
    const float* __restrict__ bout,     // [P]
    float* __restrict__ out,            // [B,T,P]
    u64* __restrict__ hbufA,            // [W/4*B] bf16x4 packs, idx k4*32+b
    u64* __restrict__ hbufB,
    u32* __restrict__ leaf,             // 8 counters, 64B apart
    u32* __restrict__ root)
{
    __shared__ float sWhh[12][WW];          // 48 KB
    __shared__ u64   sh[(WW / 4) * BB];     // 64 KB staged h (bf16x4), idx k4*32+b
    __shared__ float sPreH[2][12][BB];      // 3 KB
    __shared__ float sIg[2][2][12][BB];     // 6 KB [parity][half][row][b]
    __shared__ float sOutPart[12][64];      // 3 KB

    const int g   = blockIdx.x;
    const int tid = threadIdx.x;
    const int w0  = g * 4;

    // ---- load Whh slice into LDS ----
    for (int i = tid; i < 12 * (WW / 4); i += NTHR) {
        int row_ = i / (WW / 4);
        int k4_  = i - row_ * (WW / 4);
        int gr   = (row_ >> 2) * WW + w0 + (row_ & 3);
        *(float4*)&sWhh[row_][k4_ * 4] = *(const float4*)&Whh[(size_t)gr * WW + k4_ * 4];
    }

    // ---- P1 mapping ----
    const int  half = (tid >= 384) ? 1 : 0;
    const int  sub  = tid - half * 384;
    const int  b1   = sub & 31;
    const int  row  = sub >> 5;                 // 0..11
    const int  grow = (row >> 2) * WW + w0 + (row & 3);
    const float biasv = (half == 0) ? bias[grow] : 0.0f;

    // ---- gate-thread (tid<32) state: 4 hidden values in f32 regs ----
    float ho0 = 0.f, ho1 = 0.f, ho2 = 0.f, ho3 = 0.f;
    float bn0 = 0.f, bn1 = 0.f, bn2 = 0.f, bn3 = 0.f;
    if (tid < 32) {
        ho0 = h0[w0 + 0]; ho1 = h0[w0 + 1]; ho2 = h0[w0 + 2]; ho3 = h0[w0 + 3];
        bn0 = bias_n[w0 + 0]; bn1 = bias_n[w0 + 1]; bn2 = bias_n[w0 + 2]; bn3 = bias_n[w0 + 3];
        // init carry buffer with bf16(h0) for this WG's k4-slice, all batches
        u32 lo = bfround(ho0) | (bfround(ho1) << 16);
        u32 hi = bfround(ho2) | (bfround(ho3) << 16);
        __hip_atomic_store(&hbufA[g * 32 + tid], (u64)lo | ((u64)hi << 32),
                           __ATOMIC_RELAXED, __HIP_MEMORY_SCOPE_AGENT);
    }

    // ---- P3 mapping ----
    const int  p0  = (g & 31) * 16;
    const int  b0  = (g >> 5) * 4;
    const int  o   = tid & 63;
    const int  c   = tid >> 6;                  // 0..11
    const int  p3p = p0 + (o & 15);
    const int  p3b = b0 + (o >> 4);
    const float boutv = bout[p3p];

    // ih-dot for step t_ into parity buffer pbuf
    auto ihdot = [&](int t_, int pbuf) {
        const float4* __restrict__ arow = (const float4*)&a[((size_t)b1 * TT + t_) * PP];
        const float4* __restrict__ wrow = (const float4*)&Wih[(size_t)grow * PP];
        const int p40 = half * 64;
        float4 acc = {0.f, 0.f, 0.f, 0.f};
        #pragma unroll 8
        for (int p4 = 0; p4 < 64; ++p4) {
            float4 av = arow[p40 + p4];
            float4 wv = wrow[p40 + p4];
            acc.x += av.x * wv.x; acc.y += av.y * wv.y;
            acc.z += av.z * wv.z; acc.w += av.w * wv.w;
        }
        sIg[pbuf][half][row][b1] = (acc.x + acc.y) + (acc.z + acc.w) + biasv;
    };

    // P3 partials from staged LDS h -> sOutPart
    auto p3partials = [&]() {
        const float4* __restrict__ wrow = (const float4*)&Wout[(size_t)p3p * WW];
        float4 acc = {0.f, 0.f, 0.f, 0.f};
        for (int k4 = c; k4 < WW / 4; k4 += 12) {
            u64 pk = sh[k4 * 32 + p3b];
            float4 wv = wrow[k4];
            u32 q0 = (u32)pk, q1 = (u32)(pk >> 32);
            acc.x += __uint_as_float(q0 << 16)          * wv.x;
            acc.y += __uint_as_float(q0 & 0xffff0000u)  * wv.y;
            acc.z += __uint_as_float(q1 << 16)          * wv.z;
            acc.w += __uint_as_float(q1 & 0xffff0000u)  * wv.w;
        }
        sOutPart[c][o] = (acc.x + acc.y) + (acc.z + acc.w);
    };

    // prologue: ih-dot for first (reverse) step; parity of TT-1 is 1
    ihdot(TT - 1, 1);

    u32 rtarget = 8;
    grid_barrier(leaf, root, rtarget, g);   // h0 carry + sWhh + sIg visible

    u64* hcur = hbufA;
    u64* hnxt = hbufB;

    for (int t = TT - 1; t >= 0; --t) {
        const int par = t & 1;

        // ---- A: issue coherent loads of carry h (8192 u64 across 768 thr) ----
        u64 r0, r1, r2, r3, r4, r5, r6, r7, r8, r9, r10 = 0;
        {
            #define LDH(J) __hip_atomic_load(&hcur[tid + (J) * NTHR], __ATOMIC_RELAXED, __HIP_MEMORY_SCOPE_AGENT)
            r0 = LDH(0); r1 = LDH(1); r2 = LDH(2); r3 = LDH(3); r4 = LDH(4);
            r5 = LDH(5); r6 = LDH(6); r7 = LDH(7); r8 = LDH(8); r9 = LDH(9);
            if (tid < 512) r10 = LDH(10);
            #undef LDH
        }

        // ---- G: ih-dot for t-1 (hides the L3 latency of A) ----
        if (t > 0) ihdot(t - 1, par ^ 1);

        // ---- B: write staged h into LDS ----
        sh[tid + 0 * NTHR] = r0;  sh[tid + 1 * NTHR] = r1;  sh[tid + 2 * NTHR] = r2;
        sh[tid + 3 * NTHR] = r3;  sh[tid + 4 * NTHR] = r4;  sh[tid + 5 * NTHR] = r5;
        sh[tid + 6 * NTHR] = r6;  sh[tid + 7 * NTHR] = r7;  sh[tid + 8 * NTHR] = r8;
        sh[tid + 9 * NTHR] = r9;
        if (tid < 512) sh[tid + 10 * NTHR] = r10;
        __syncthreads();

        // ---- D: hh-dot from LDS ----
        {
            const int k40 = half * 128;
            float4 acc = {0.f, 0.f, 0.f, 0.f};
            #pragma unroll 4
            for (int k4 = 0; k4 < 128; ++k4) {
                u64 pk = sh[(k40 + k4) * 32 + b1];
                float4 wv = *(const float4*)&sWhh[row][(k40 + k4) * 4];
                u32 q0 = (u32)pk, q1 = (u32)(pk >> 32);
                acc.x += __uint_as_float(q0 << 16)          * wv.x;
                acc.y += __uint_as_float(q0 & 0xffff0000u)  * wv.y;
                acc.z += __uint_as_float(q1 << 16)          * wv.z;
                acc.w += __uint_as_float(q1 & 0xffff0000u)  * wv.w;
            }
            sPreH[half][row][b1] = (acc.x + acc.y) + (acc.z + acc.w);
        }
        // ---- P3 partials for h_{t+1} (the carry we just staged) ----
        if (t < TT - 1) p3partials();
        __syncthreads();

        // ---- F: gates + h update (tid<32, 4 w's each) ----
        if (tid < 32) {
            float hn0, hn1, hn2, hn3;
            {
                float ir = sIg[par][0][0][tid] + sIg[par][1][0][tid];
                float hr = sPreH[0][0][tid] + sPreH[1][0][tid];
                float iz = sIg[par][0][4][tid] + sIg[par][1][4][tid];
                float hz = sPreH[0][4][tid] + sPreH[1][4][tid];
                float in_ = sIg[par][0][8][tid] + sIg[par][1][8][tid];
                float hn_ = sPreH[0][8][tid] + sPreH[1][8][tid];
                float rr = 1.f / (1.f + __expf(-(ir + hr)));
                float zz = 1.f / (1.f + __expf(-(iz + hz)));
                float nn = tanhf(in_ + rr * (hn_ + bn0));
                hn0 = nn + zz * (ho0 - nn); ho0 = hn0;
            }
            {
                float ir = sIg[par][0][1][tid] + sIg[par][1][1][tid];
                float hr = sPreH[0][1][tid] + sPreH[1][1][tid];
                float iz = sIg[par][0][5][tid] + sIg[par][1][5][tid];
                float hz = sPreH[0][5][tid] + sPreH[1][5][tid];
                float in_ = sIg[par][0][9][tid] + sIg[par][1][9][tid];
                float hn_ = sPreH[0][9][tid] + sPreH[1][9][tid];
                float rr = 1.f / (1.f + __expf(-(ir + hr)));
                float zz = 1.f / (1.f + __expf(-(iz + hz)));
                float nn = tanhf(in_ + rr * (hn_ + bn1));
                hn1 = nn + zz * (ho1 - nn); ho1 = hn1;
            }
            {
                float ir = sIg[par][0][2][tid] + sIg[par][1][2][tid];
                float hr = sPreH[0][2][tid] + sPreH[1][2][tid];
                float iz = sIg[par][0][6][tid] + sIg[par][1][6][tid];
                float hz = sPreH[0][6][tid] + sPreH[1][6][tid];
                float in_ = sIg[par][0][10][tid] + sIg[par][1][10][tid];
                float hn_ = sPreH[0][10][tid] + sPreH[1][10][tid];
                float rr = 1.f / (1.f + __expf(-(ir + hr)));
                float zz = 1.f / (1.f + __expf(-(iz + hz)));
                float nn = tanhf(in_ + rr * (hn_ + bn2));
                hn2 = nn + zz * (ho2 - nn); ho2 = hn2;
            }
            {
                float ir = sIg[par][0][3][tid] + sIg[par][1][3][tid];
                float hr = sPreH[0][3][tid] + sPreH[1][3][tid];
                float iz = sIg[par][0][7][tid] + sIg[par][1][7][tid];
                float hz = sPreH[0][7][tid] + sPreH[1][7][tid];
                float in_ = sIg[par][0][11][tid] + sIg[par][1][11][tid];
                float hn_ = sPreH[0][11][tid] + sPreH[1][11][tid];
                float rr = 1.f / (1.f + __expf(-(ir + hr)));
                float zz = 1.f / (1.f + __expf(-(iz + hz)));
                float nn = tanhf(in_ + rr * (hn_ + bn3));
                hn3 = nn + zz * (ho3 - nn); ho3 = hn3;
            }
            u32 lo = bfround(hn0) | (bfround(hn1) << 16);
            u32 hi = bfround(hn2) | (bfround(hn3) << 16);
            __hip_atomic_store(&hnxt[g * 32 + tid], (u64)lo | ((u64)hi << 32),
                               __ATOMIC_RELAXED, __HIP_MEMORY_SCOPE_AGENT);
        }
        // ---- out[t+1] reduce + store ----
        if (t < TT - 1 && tid < 64) {
            float s_ = boutv;
            #pragma unroll
            for (int cc = 0; cc < 12; ++cc) s_ += sOutPart[cc][o];
            out[((size_t)p3b * TT + (t + 1)) * PP + p3p] = s_;
        }

        rtarget += 8;
        grid_barrier(leaf, root, rtarget, g);
        u64* tmp = hcur; hcur = hnxt; hnxt = tmp;
    }

    // ---- epilogue: stage h_0, project -> out[0] ----
    {
        u64 r0, r1, r2, r3, r4, r5, r6, r7, r8, r9, r10 = 0;
        #define LDH(J) __hip_atomic_load(&hcur[tid + (J) * NTHR], __ATOMIC_RELAXED, __HIP_MEMORY_SCOPE_AGENT)
        r0 = LDH(0); r1 = LDH(1); r2 = LDH(2); r3 = LDH(3); r4 = LDH(4);
        r5 = LDH(5); r6 = LDH(6); r7 = LDH(7); r8 = LDH(8); r9 = LDH(9);
        if (tid < 512) r10 = LDH(10);
        #undef LDH
        sh[tid + 0 * NTHR] = r0;  sh[tid + 1 * NTHR] = r1;  sh[tid + 2 * NTHR] = r2;
        sh[tid + 3 * NTHR] = r3;  sh[tid + 4 * NTHR] = r4;  sh[tid + 5 * NTHR] = r5;
        sh[tid + 6 * NTHR] = r6;  sh[tid + 7 * NTHR] = r7;  sh[tid + 8 * NTHR] = r8;
        sh[tid + 9 * NTHR] = r9;
        if (tid < 512) sh[tid + 10 * NTHR] = r10;
        __syncthreads();
        p3partials();
        __syncthreads();
        if (tid < 64) {
            float s_ = boutv;
            #pragma unroll
            for (int cc = 0; cc < 12; ++cc) s_ += sOutPart[cc][o];
            out[((size_t)p3b * TT + 0) * PP + p3p] = s_;
        }
    }
}

extern "C" void kernel_launch(void* const* d_in, const int* in_sizes, int n_in,
                              void* d_out, int out_size, void* d_ws, size_t ws_size,
                              hipStream_t stream) {
    const float* a      = (const float*)d_in[0];
    const float* h0     = (const float*)d_in[1];
    const float* Wih    = (const float*)d_in[2];
    const float* Whh    = (const float*)d_in[3];
    const float* bias   = (const float*)d_in[4];
    const float* bias_n = (const float*)d_in[5];
    const float* Wout   = (const float*)d_in[6];
    const float* bout   = (const float*)d_in[7];
    float* out = (float*)d_out;

    u64* hA   = (u64*)d_ws;                              // 8192 u64 = 64 KB
    u64* hB   = hA + (WW / 4) * BB;                      // 64 KB
    u32* leaf = (u32*)((char*)d_ws + 2 * 65536);         // 8 x 64B
    u32* root = leaf + 8 * 16;                           // next 64B line

    hipMemsetAsync(leaf, 0, 1024, stream);               // leaves + root

    void* args[] = {(void*)&a, (void*)&h0, (void*)&Wih, (void*)&Whh,
                    (void*)&bias, (void*)&bias_n, (void*)&Wout, (void*)&bout,
                    (void*)&out, (void*)&hA, (void*)&hB, (void*)&leaf, (void*)&root};
    hipLaunchCooperativeKernel((void*)gru_scan_kernel, dim3(NWG), dim3(NTHR),
                               args, 0, stream);
}

// Round 4
// 101256.378 us; speedup vs baseline: 3.0025x; 1.7720x over previous
//
#include <hip/hip_runtime.h>
#include <cstddef>

#define BB 32
#define TT 4096
#define PP 512
#define WW 1024

constexpr int NWG  = 256;
constexpr int NTHR = 768;

using u32 = unsigned;
using u64 = unsigned long long;

__device__ __forceinline__ u32 bfround(float f) {
    u32 u = __float_as_uint(f);
    return (u + 0x7fffu + ((u >> 16) & 1u)) >> 16;
}
__device__ __forceinline__ float bflo(u32 q) { return __uint_as_float(q << 16); }
__device__ __forceinline__ float bfhi(u32 q) { return __uint_as_float(q & 0xffff0000u); }

__device__ __forceinline__ void grid_barrier(u32* leaf, u32* root, u32 rtarget, int g) {
    asm volatile("s_waitcnt vmcnt(0)" ::: "memory");
    __syncthreads();
    if (threadIdx.x == 0) {
        u32 old = __hip_atomic_fetch_add(&leaf[(g & 7) * 16], 1u,
                                         __ATOMIC_RELAXED, __HIP_MEMORY_SCOPE_AGENT);
        if ((old & 31u) == 31u)
            __hip_atomic_fetch_add(root, 1u, __ATOMIC_RELAXED, __HIP_MEMORY_SCOPE_AGENT);
        while (__hip_atomic_load(root, __ATOMIC_RELAXED, __HIP_MEMORY_SCOPE_AGENT) < rtarget)
            __builtin_amdgcn_s_sleep(2);
    }
    __syncthreads();
}

// ============================ PREPASS ============================
// ig[t][gWG][12 rows][32 b] bf16.  grid (96 gate-groups, 64 t-chunks), 256 thr.
__global__ __launch_bounds__(256, 1) void ig_prepass(
    const float* __restrict__ a, const float* __restrict__ Wih,
    const float* __restrict__ bias, char* __restrict__ igbase)
{
    __shared__ float aLds[32][516];
    __shared__ float pp[8][32][33];
    __shared__ float sBias[32];

    const int tid = threadIdx.x;
    const int gg  = blockIdx.x;          // 0..95  (32 gate-rows each)
    const int t0  = blockIdx.y * 64;
    const int gr  = tid & 31;
    const int kc  = tid >> 5;            // 0..7 (k-chunk of 64)
    const int grow = gg * 32 + gr;

    float4 wreg[16];
    {
        const float4* wr = (const float4*)&Wih[(size_t)grow * PP + kc * 64];
        #pragma unroll
        for (int j = 0; j < 16; ++j) wreg[j] = wr[j];
    }
    if (tid < 32) sBias[tid] = bias[gg * 32 + tid];

    const int sb = tid >> 3, sseg = tid & 7;
    const float* abase = &a[(size_t)sb * TT * PP];
    float4 st[16];
    {
        const float4* p = (const float4*)&abase[(size_t)t0 * PP + sseg * 64];
        #pragma unroll
        for (int j = 0; j < 16; ++j) st[j] = p[j];
    }

    for (int t = t0; t < t0 + 64; ++t) {
        __syncthreads();
        #pragma unroll
        for (int j = 0; j < 16; ++j)
            *(float4*)&aLds[sb][sseg * 64 + j * 4] = st[j];
        __syncthreads();
        if (t + 1 < t0 + 64) {
            const float4* p = (const float4*)&abase[(size_t)(t + 1) * PP + sseg * 64];
            #pragma unroll
            for (int j = 0; j < 16; ++j) st[j] = p[j];
        }
        float acc[32];
        #pragma unroll
        for (int b = 0; b < 32; ++b) acc[b] = 0.f;
        #pragma unroll
        for (int k4 = 0; k4 < 16; ++k4) {
            float4 wv = wreg[k4];
            #pragma unroll
            for (int b = 0; b < 32; ++b) {
                float4 av = *(const float4*)&aLds[b][kc * 64 + k4 * 4];
                acc[b] += wv.x * av.x + wv.y * av.y + wv.z * av.z + wv.w * av.w;
            }
        }
        #pragma unroll
        for (int b = 0; b < 32; ++b) pp[kc][gr][b] = acc[b];
        __syncthreads();
        {
            const int rg = tid >> 3;
            const int b0 = (tid & 7) * 4;
            float v[4];
            #pragma unroll
            for (int e = 0; e < 4; ++e) {
                float s = sBias[rg];
                #pragma unroll
                for (int k2 = 0; k2 < 8; ++k2) s += pp[k2][rg][b0 + e];
                v[e] = s;
            }
            uint2 pk;
            pk.x = bfround(v[0]) | (bfround(v[1]) << 16);
            pk.y = bfround(v[2]) | (bfround(v[3]) << 16);
            const int grow2 = gg * 32 + rg;
            const int gate  = grow2 >> 10;
            const int w     = grow2 & 1023;
            const int gWG   = w >> 2;
            const int r     = gate * 4 + (w & 3);
            *(uint2*)(igbase + ((size_t)t * 256 + gWG) * 768 + r * 64 + b0 * 2) = pk;
        }
    }
}

// ============================ SCAN (ig hoisted) ============================
__global__ __launch_bounds__(NTHR, 1) void gru_scan2(
    const float* __restrict__ h0, const float* __restrict__ Whh,
    const float* __restrict__ bias_n, const float* __restrict__ Wout,
    const float* __restrict__ bout, const char* __restrict__ igbase,
    float* __restrict__ out, u64* __restrict__ hbufA, u64* __restrict__ hbufB,
    u32* __restrict__ leaf, u32* __restrict__ root)
{
    __shared__ float sWhh[12][WW];           // 48 KB f32
    __shared__ u64   sh[8192];               // 64 KB bf16 h, linear = (k8*32+b)*2+p
    __shared__ float sPreH[2][12][BB];
    __shared__ u64   sIgRaw[96];
    __shared__ float sOutPart[12][64];

    const int g   = blockIdx.x;
    const int tid = threadIdx.x;
    const int w0  = g * 4;

    for (int i = tid; i < 12 * (WW / 4); i += NTHR) {
        int row_ = i / (WW / 4);
        int k4_  = i - row_ * (WW / 4);
        int gr   = (row_ >> 2) * WW + w0 + (row_ & 3);
        *(float4*)&sWhh[row_][k4_ * 4] = *(const float4*)&Whh[(size_t)gr * WW + k4_ * 4];
    }

    // P1 mapping
    const int  half = (tid >= 384) ? 1 : 0;
    const int  sub  = tid - half * 384;
    const int  b1   = sub & 31;
    const int  row  = sub >> 5;

    // gate-thread state
    float ho0 = 0.f, ho1 = 0.f, ho2 = 0.f, ho3 = 0.f;
    float bn0 = 0.f, bn1 = 0.f, bn2 = 0.f, bn3 = 0.f;
    const int hidx = (((g >> 1) * 32 + tid) << 1) + (g & 1);   // valid for tid<32
    if (tid < 32) {
        ho0 = h0[w0 + 0]; ho1 = h0[w0 + 1]; ho2 = h0[w0 + 2]; ho3 = h0[w0 + 3];
        bn0 = bias_n[w0 + 0]; bn1 = bias_n[w0 + 1]; bn2 = bias_n[w0 + 2]; bn3 = bias_n[w0 + 3];
        u32 lo = bfround(ho0) | (bfround(ho1) << 16);
        u32 hi = bfround(ho2) | (bfround(ho3) << 16);
        __hip_atomic_store(&hbufA[hidx], (u64)lo | ((u64)hi << 32),
                           __ATOMIC_RELAXED, __HIP_MEMORY_SCOPE_AGENT);
    }

    // P3 mapping
    const int  p0  = (g & 31) * 16;
    const int  b0  = (g >> 5) * 4;
    const int  o   = tid & 63;
    const int  c   = tid >> 6;
    const int  p3p = p0 + (o & 15);
    const int  p3b = b0 + (o >> 4);
    const float boutv = bout[p3p];

    const uint4* shv = (const uint4*)sh;

    auto p3partials = [&]() {
        const float4* __restrict__ wrow = (const float4*)&Wout[(size_t)p3p * WW];
        float a0 = 0.f, a1 = 0.f, a2 = 0.f, a3 = 0.f;
        for (int k8 = c; k8 < 128; k8 += 12) {
            uint4 q = shv[k8 * 32 + p3b];
            float4 v0 = wrow[k8 * 2], v1 = wrow[k8 * 2 + 1];
            a0 += v0.x * bflo(q.x); a1 += v0.y * bfhi(q.x);
            a2 += v0.z * bflo(q.y); a3 += v0.w * bfhi(q.y);
            a0 += v1.x * bflo(q.z); a1 += v1.y * bfhi(q.z);
            a2 += v1.z * bflo(q.w); a3 += v1.w * bfhi(q.w);
        }
        sOutPart[c][o] = (a0 + a1) + (a2 + a3);
    };

    u32 rtarget = 8;
    grid_barrier(leaf, root, rtarget, g);

    u64* hcur = hbufA;
    u64* hnxt = hbufB;

    for (int t = TT - 1; t >= 0; --t) {
        // A: coherent loads of carry h
        u64 r0, r1, r2, r3, r4, r5, r6, r7, r8, r9, r10 = 0;
        #define LDH(J) __hip_atomic_load(&hcur[tid + (J) * NTHR], __ATOMIC_RELAXED, __HIP_MEMORY_SCOPE_AGENT)
        r0 = LDH(0); r1 = LDH(1); r2 = LDH(2); r3 = LDH(3); r4 = LDH(4);
        r5 = LDH(5); r6 = LDH(6); r7 = LDH(7); r8 = LDH(8); r9 = LDH(9);
        if (tid < 512) r10 = LDH(10);
        #undef LDH
        // ig slice load (consumed at gate phase)
        u64 igr = 0;
        if (tid < 96)
            igr = *(const u64*)(igbase + ((size_t)t * 256 + g) * 768 + tid * 8);

        sh[tid + 0 * NTHR] = r0;  sh[tid + 1 * NTHR] = r1;  sh[tid + 2 * NTHR] = r2;
        sh[tid + 3 * NTHR] = r3;  sh[tid + 4 * NTHR] = r4;  sh[tid + 5 * NTHR] = r5;
        sh[tid + 6 * NTHR] = r6;  sh[tid + 7 * NTHR] = r7;  sh[tid + 8 * NTHR] = r8;
        sh[tid + 9 * NTHR] = r9;
        if (tid < 512) sh[tid + 10 * NTHR] = r10;
        __syncthreads();

        // D: hh-dot, 64 iters of 8 k
        {
            float a0 = 0.f, a1 = 0.f, a2 = 0.f, a3 = 0.f;
            const int kb = half * 64;
            #pragma unroll 4
            for (int k8 = 0; k8 < 64; ++k8) {
                uint4 q = shv[(kb + k8) * 32 + b1];
                const float* wp = &sWhh[row][(kb + k8) * 8];
                float4 v0 = *(const float4*)wp;
                float4 v1 = *(const float4*)(wp + 4);
                a0 += v0.x * bflo(q.x); a1 += v0.y * bfhi(q.x);
                a2 += v0.z * bflo(q.y); a3 += v0.w * bfhi(q.y);
                a0 += v1.x * bflo(q.z); a1 += v1.y * bfhi(q.z);
                a2 += v1.z * bflo(q.w); a3 += v1.w * bfhi(q.w);
            }
            sPreH[half][row][b1] = (a0 + a1) + (a2 + a3);
        }
        if (t < TT - 1) p3partials();
        if (tid < 96) sIgRaw[tid] = igr;
        __syncthreads();

        // F: gates
        if (tid < 32) {
            const unsigned short* sIgU = (const unsigned short*)sIgRaw;
            const int b = tid;
            #define IGV(R) __uint_as_float((u32)sIgU[(R) * 32 + b] << 16)
            float hn0, hn1, hn2, hn3;
            {
                float rr = 1.f / (1.f + __expf(-(IGV(0) + sPreH[0][0][b] + sPreH[1][0][b])));
                float zz = 1.f / (1.f + __expf(-(IGV(4) + sPreH[0][4][b] + sPreH[1][4][b])));
                float nn = tanhf(IGV(8) + rr * (sPreH[0][8][b] + sPreH[1][8][b] + bn0));
                hn0 = nn + zz * (ho0 - nn); ho0 = hn0;
            }
            {
                float rr = 1.f / (1.f + __expf(-(IGV(1) + sPreH[0][1][b] + sPreH[1][1][b])));
                float zz = 1.f / (1.f + __expf(-(IGV(5) + sPreH[0][5][b] + sPreH[1][5][b])));
                float nn = tanhf(IGV(9) + rr * (sPreH[0][9][b] + sPreH[1][9][b] + bn1));
                hn1 = nn + zz * (ho1 - nn); ho1 = hn1;
            }
            {
                float rr = 1.f / (1.f + __expf(-(IGV(2) + sPreH[0][2][b] + sPreH[1][2][b])));
                float zz = 1.f / (1.f + __expf(-(IGV(6) + sPreH[0][6][b] + sPreH[1][6][b])));
                float nn = tanhf(IGV(10) + rr * (sPreH[0][10][b] + sPreH[1][10][b] + bn2));
                hn2 = nn + zz * (ho2 - nn); ho2 = hn2;
            }
            {
                float rr = 1.f / (1.f + __expf(-(IGV(3) + sPreH[0][3][b] + sPreH[1][3][b])));
                float zz = 1.f / (1.f + __expf(-(IGV(7) + sPreH[0][7][b] + sPreH[1][7][b])));
                float nn = tanhf(IGV(11) + rr * (sPreH[0][11][b] + sPreH[1][11][b] + bn3));
                hn3 = nn + zz * (ho3 - nn); ho3 = hn3;
            }
            #undef IGV
            u32 lo = bfround(hn0) | (bfround(hn1) << 16);
            u32 hi = bfround(hn2) | (bfround(hn3) << 16);
            __hip_atomic_store(&hnxt[hidx], (u64)lo | ((u64)hi << 32),
                               __ATOMIC_RELAXED, __HIP_MEMORY_SCOPE_AGENT);
        }
        if (t < TT - 1 && tid < 64) {
            float s_ = boutv;
            #pragma unroll
            for (int cc = 0; cc < 12; ++cc) s_ += sOutPart[cc][o];
            out[((size_t)p3b * TT + (t + 1)) * PP + p3p] = s_;
        }

        rtarget += 8;
        grid_barrier(leaf, root, rtarget, g);
        u64* tmp = hcur; hcur = hnxt; hnxt = tmp;
    }

    // epilogue: project h_0 -> out[0]
    {
        u64 r0, r1, r2, r3, r4, r5, r6, r7, r8, r9, r10 = 0;
        #define LDH(J) __hip_atomic_load(&hcur[tid + (J) * NTHR], __ATOMIC_RELAXED, __HIP_MEMORY_SCOPE_AGENT)
        r0 = LDH(0); r1 = LDH(1); r2 = LDH(2); r3 = LDH(3); r4 = LDH(4);
        r5 = LDH(5); r6 = LDH(6); r7 = LDH(7); r8 = LDH(8); r9 = LDH(9);
        if (tid < 512) r10 = LDH(10);
        #undef LDH
        sh[tid + 0 * NTHR] = r0;  sh[tid + 1 * NTHR] = r1;  sh[tid + 2 * NTHR] = r2;
        sh[tid + 3 * NTHR] = r3;  sh[tid + 4 * NTHR] = r4;  sh[tid + 5 * NTHR] = r5;
        sh[tid + 6 * NTHR] = r6;  sh[tid + 7 * NTHR] = r7;  sh[tid + 8 * NTHR] = r8;
        sh[tid + 9 * NTHR] = r9;
        if (tid < 512) sh[tid + 10 * NTHR] = r10;
        __syncthreads();
        p3partials();
        __syncthreads();
        if (tid < 64) {
            float s_ = boutv;
            #pragma unroll
            for (int cc = 0; cc < 12; ++cc) s_ += sOutPart[cc][o];
            out[((size_t)p3b * TT + 0) * PP + p3p] = s_;
        }
    }
}

// ===================== FALLBACK (proven R3 kernel) =====================
__global__ __launch_bounds__(NTHR, 1) void gru_scan_fb(
    const float* __restrict__ a, const float* __restrict__ h0,
    const float* __restrict__ Wih, const float* __restrict__ Whh,
    const float* __restrict__ bias, const float* __restrict__ bias_n,
    const float* __restrict__ Wout, const float* __restrict__ bout,
    float* __restrict__ out, u64* __restrict__ hbufA, u64* __restrict__ hbufB,
    u32* __restrict__ leaf, u32* __restrict__ root)
{
    __shared__ float sWhh[12][WW];
    __shared__ u64   sh[8192];
    __shared__ float sPreH[2][12][BB];
    __shared__ float sIg[2][2][12][BB];
    __shared__ float sOutPart[12][64];

    const int g   = blockIdx.x;
    const int tid = threadIdx.x;
    const int w0  = g * 4;

    for (int i = tid; i < 12 * (WW / 4); i += NTHR) {
        int row_ = i / (WW / 4);
        int k4_  = i - row_ * (WW / 4);
        int gr   = (row_ >> 2) * WW + w0 + (row_ & 3);
        *(float4*)&sWhh[row_][k4_ * 4] = *(const float4*)&Whh[(size_t)gr * WW + k4_ * 4];
    }
    const int  half = (tid >= 384) ? 1 : 0;
    const int  sub  = tid - half * 384;
    const int  b1   = sub & 31;
    const int  row  = sub >> 5;
    const int  grow = (row >> 2) * WW + w0 + (row & 3);
    const float biasv = (half == 0) ? bias[grow] : 0.0f;

    float ho0 = 0.f, ho1 = 0.f, ho2 = 0.f, ho3 = 0.f;
    float bn0 = 0.f, bn1 = 0.f, bn2 = 0.f, bn3 = 0.f;
    if (tid < 32) {
        ho0 = h0[w0 + 0]; ho1 = h0[w0 + 1]; ho2 = h0[w0 + 2]; ho3 = h0[w0 + 3];
        bn0 = bias_n[w0 + 0]; bn1 = bias_n[w0 + 1]; bn2 = bias_n[w0 + 2]; bn3 = bias_n[w0 + 3];
        u32 lo = bfround(ho0) | (bfround(ho1) << 16);
        u32 hi = bfround(ho2) | (bfround(ho3) << 16);
        __hip_atomic_store(&hbufA[g * 32 + tid], (u64)lo | ((u64)hi << 32),
                           __ATOMIC_RELAXED, __HIP_MEMORY_SCOPE_AGENT);
    }
    const int  p0  = (g & 31) * 16;
    const int  b0  = (g >> 5) * 4;
    const int  o   = tid & 63;
    const int  c   = tid >> 6;
    const int  p3p = p0 + (o & 15);
    const int  p3b = b0 + (o >> 4);
    const float boutv = bout[p3p];

    auto ihdot = [&](int t_, int pbuf) {
        const float4* __restrict__ arow = (const float4*)&a[((size_t)b1 * TT + t_) * PP];
        const float4* __restrict__ wrow = (const float4*)&Wih[(size_t)grow * PP];
        const int p40 = half * 64;
        float4 acc = {0.f, 0.f, 0.f, 0.f};
        #pragma unroll 8
        for (int p4 = 0; p4 < 64; ++p4) {
            float4 av = arow[p40 + p4];
            float4 wv = wrow[p40 + p4];
            acc.x += av.x * wv.x; acc.y += av.y * wv.y;
            acc.z += av.z * wv.z; acc.w += av.w * wv.w;
        }
        sIg[pbuf][half][row][b1] = (acc.x + acc.y) + (acc.z + acc.w) + biasv;
    };
    auto p3partials = [&]() {
        const float4* __restrict__ wrow = (const float4*)&Wout[(size_t)p3p * WW];
        float4 acc = {0.f, 0.f, 0.f, 0.f};
        for (int k4 = c; k4 < WW / 4; k4 += 12) {
            u64 pk = sh[k4 * 32 + p3b];
            float4 wv = wrow[k4];
            acc.x += bflo((u32)pk) * wv.x;
            acc.y += bfhi((u32)pk) * wv.y;
            acc.z += bflo((u32)(pk >> 32)) * wv.z;
            acc.w += bfhi((u32)(pk >> 32)) * wv.w;
        }
        sOutPart[c][o] = (acc.x + acc.y) + (acc.z + acc.w);
    };

    ihdot(TT - 1, 1);
    u32 rtarget = 8;
    grid_barrier(leaf, root, rtarget, g);
    u64* hcur = hbufA;
    u64* hnxt = hbufB;

    for (int t = TT - 1; t >= 0; --t) {
        const int par = t & 1;
        u64 r0, r1, r2, r3, r4, r5, r6, r7, r8, r9, r10 = 0;
        #define LDH(J) __hip_atomic_load(&hcur[tid + (J) * NTHR], __ATOMIC_RELAXED, __HIP_MEMORY_SCOPE_AGENT)
        r0 = LDH(0); r1 = LDH(1); r2 = LDH(2); r3 = LDH(3); r4 = LDH(4);
        r5 = LDH(5); r6 = LDH(6); r7 = LDH(7); r8 = LDH(8); r9 = LDH(9);
        if (tid < 512) r10 = LDH(10);
        #undef LDH
        if (t > 0) ihdot(t - 1, par ^ 1);
        sh[tid + 0 * NTHR] = r0;  sh[tid + 1 * NTHR] = r1;  sh[tid + 2 * NTHR] = r2;
        sh[tid + 3 * NTHR] = r3;  sh[tid + 4 * NTHR] = r4;  sh[tid + 5 * NTHR] = r5;
        sh[tid + 6 * NTHR] = r6;  sh[tid + 7 * NTHR] = r7;  sh[tid + 8 * NTHR] = r8;
        sh[tid + 9 * NTHR] = r9;
        if (tid < 512) sh[tid + 10 * NTHR] = r10;
        __syncthreads();
        {
            const int k40 = half * 128;
            float4 acc = {0.f, 0.f, 0.f, 0.f};
            #pragma unroll 4
            for (int k4 = 0; k4 < 128; ++k4) {
                u64 pk = sh[(k40 + k4) * 32 + b1];
                float4 wv = *(const float4*)&sWhh[row][(k40 + k4) * 4];
                acc.x += bflo((u32)pk) * wv.x;
                acc.y += bfhi((u32)pk) * wv.y;
                acc.z += bflo((u32)(pk >> 32)) * wv.z;
                acc.w += bfhi((u32)(pk >> 32)) * wv.w;
            }
            sPreH[half][row][b1] = (acc.x + acc.y) + (acc.z + acc.w);
        }
        if (t < TT - 1) p3partials();
        __syncthreads();
        if (tid < 32) {
            const int b = tid;
            float hn0, hn1, hn2, hn3;
            {
                float rr = 1.f / (1.f + __expf(-(sIg[par][0][0][b] + sIg[par][1][0][b] + sPreH[0][0][b] + sPreH[1][0][b])));
                float zz = 1.f / (1.f + __expf(-(sIg[par][0][4][b] + sIg[par][1][4][b] + sPreH[0][4][b] + sPreH[1][4][b])));
                float nn = tanhf(sIg[par][0][8][b] + sIg[par][1][8][b] + rr * (sPreH[0][8][b] + sPreH[1][8][b] + bn0));
                hn0 = nn + zz * (ho0 - nn); ho0 = hn0;
            }
            {
                float rr = 1.f / (1.f + __expf(-(sIg[par][0][1][b] + sIg[par][1][1][b] + sPreH[0][1][b] + sPreH[1][1][b])));
                float zz = 1.f / (1.f + __expf(-(sIg[par][0][5][b] + sIg[par][1][5][b] + sPreH[0][5][b] + sPreH[1][5][b])));
                float nn = tanhf(sIg[par][0][9][b] + sIg[par][1][9][b] + rr * (sPreH[0][9][b] + sPreH[1][9][b] + bn1));
                hn1 = nn + zz * (ho1 - nn); ho1 = hn1;
            }
            {
                float rr = 1.f / (1.f + __expf(-(sIg[par][0][2][b] + sIg[par][1][2][b] + sPreH[0][2][b] + sPreH[1][2][b])));
                float zz = 1.f / (1.f + __expf(-(sIg[par][0][6][b] + sIg[par][1][6][b] + sPreH[0][6][b] + sPreH[1][6][b])));
                float nn = tanhf(sIg[par][0][10][b] + sIg[par][1][10][b] + rr * (sPreH[0][10][b] + sPreH[1][10][b] + bn2));
                hn2 = nn + zz * (ho2 - nn); ho2 = hn2;
            }
            {
                float rr = 1.f / (1.f + __expf(-(sIg[par][0][3][b] + sIg[par][1][3][b] + sPreH[0][3][b] + sPreH[1][3][b])));
                float zz = 1.f / (1.f + __expf(-(sIg[par][0][7][b] + sIg[par][1][7][b] + sPreH[0][7][b] + sPreH[1][7][b])));
                float nn = tanhf(sIg[par][0][11][b] + sIg[par][1][11][b] + rr * (sPreH[0][11][b] + sPreH[1][11][b] + bn3));
                hn3 = nn + zz * (ho3 - nn); ho3 = hn3;
            }
            u32 lo = bfround(hn0) | (bfround(hn1) << 16);
            u32 hi = bfround(hn2) | (bfround(hn3) << 16);
            __hip_atomic_store(&hnxt[g * 32 + tid], (u64)lo | ((u64)hi << 32),
                               __ATOMIC_RELAXED, __HIP_MEMORY_SCOPE_AGENT);
        }
        if (t < TT - 1 && tid < 64) {
            float s_ = boutv;
            #pragma unroll
            for (int cc = 0; cc < 12; ++cc) s_ += sOutPart[cc][o];
            out[((size_t)p3b * TT + (t + 1)) * PP + p3p] = s_;
        }
        rtarget += 8;
        grid_barrier(leaf, root, rtarget, g);
        u64* tmp = hcur; hcur = hnxt; hnxt = tmp;
    }
    {
        u64 r0, r1, r2, r3, r4, r5, r6, r7, r8, r9, r10 = 0;
        #define LDH(J) __hip_atomic_load(&hcur[tid + (J) * NTHR], __ATOMIC_RELAXED, __HIP_MEMORY_SCOPE_AGENT)
        r0 = LDH(0); r1 = LDH(1); r2 = LDH(2); r3 = LDH(3); r4 = LDH(4);
        r5 = LDH(5); r6 = LDH(6); r7 = LDH(7); r8 = LDH(8); r9 = LDH(9);
        if (tid < 512) r10 = LDH(10);
        #undef LDH
        sh[tid + 0 * NTHR] = r0;  sh[tid + 1 * NTHR] = r1;  sh[tid + 2 * NTHR] = r2;
        sh[tid + 3 * NTHR] = r3;  sh[tid + 4 * NTHR] = r4;  sh[tid + 5 * NTHR] = r5;
        sh[tid + 6 * NTHR] = r6;  sh[tid + 7 * NTHR] = r7;  sh[tid + 8 * NTHR] = r8;
        sh[tid + 9 * NTHR] = r9;
        if (tid < 512) sh[tid + 10 * NTHR] = r10;
        __syncthreads();
        p3partials();
        __syncthreads();
        if (tid < 64) {
            float s_ = boutv;
            #pragma unroll
            for (int cc = 0; cc < 12; ++cc) s_ += sOutPart[cc][o];
            out[((size_t)p3b * TT + 0) * PP + p3p] = s_;
        }
    }
}

extern "C" void kernel_launch(void* const* d_in, const int* in_sizes, int n_in,
                              void* d_out, int out_size, void* d_ws, size_t ws_size,
                              hipStream_t stream) {
    const float* a      = (const float*)d_in[0];
    const float* h0     = (const float*)d_in[1];
    const float* Wih    = (const float*)d_in[2];
    const float* Whh    = (const float*)d_in[3];
    const float* bias   = (const float*)d_in[4];
    const float* bias_n = (const float*)d_in[5];
    const float* Wout   = (const float*)d_in[6];
    const float* bout   = (const float*)d_in[7];
    float* out = (float*)d_out;

    const size_t IG_BYTES = (size_t)TT * 256 * 768;          // 805,306,368
    const size_t NEED     = IG_BYTES + 2 * 65536 + 1024;

    if (ws_size >= NEED) {
        char* igbase = (char*)d_ws;
        u64*  hA   = (u64*)((char*)d_ws + IG_BYTES);
        u64*  hB   = hA + 8192;
        u32*  leaf = (u32*)((char*)d_ws + IG_BYTES + 2 * 65536);
        u32*  root = leaf + 8 * 16;
        hipMemsetAsync(leaf, 0, 1024, stream);
        hipLaunchKernelGGL(ig_prepass, dim3(96, 64), dim3(256), 0, stream,
                           a, Wih, bias, igbase);
        void* args[] = {(void*)&h0, (void*)&Whh, (void*)&bias_n, (void*)&Wout,
                        (void*)&bout, (void*)&igbase, (void*)&out,
                        (void*)&hA, (void*)&hB, (void*)&leaf, (void*)&root};
        hipLaunchCooperativeKernel((void*)gru_scan2, dim3(NWG), dim3(NTHR),
                                   args, 0, stream);
    } else {
        u64* hA   = (u64*)d_ws;
        u64* hB   = hA + 8192;
        u32* leaf = (u32*)((char*)d_ws + 2 * 65536);
        u32* root = leaf + 8 * 16;
        hipMemsetAsync(leaf, 0, 1024, stream);
        void* args[] = {(void*)&a, (void*)&h0, (void*)&Wih, (void*)&Whh,
                        (void*)&bias, (void*)&bias_n, (void*)&Wout, (void*)&bout,
                        (void*)&out, (void*)&hA, (void*)&hB, (void*)&leaf, (void*)&root};
        hipLaunchCooperativeKernel((void*)gru_scan_fb, dim3(NWG), dim3(NTHR),
                                   args, 0, stream);
    }
}

// Round 5
// 26419.540 us; speedup vs baseline: 11.5076x; 3.8326x over previous
//
#include <hip/hip_runtime.h>
#include <cstddef>

#define BB 32
#define TT 4096
#define PP 512
#define WW 1024

using u32 = unsigned;
using u64 = unsigned long long;

typedef short short8 __attribute__((ext_vector_type(8)));
typedef float f32x4 __attribute__((ext_vector_type(4)));

__device__ __forceinline__ u32 bfround(float f) {
    u32 u = __float_as_uint(f);
    return (u + 0x7fffu + ((u >> 16) & 1u)) >> 16;
}
__device__ __forceinline__ float bf2f(u32 q) { return __uint_as_float(q << 16); }
__device__ __forceinline__ float bflo(u32 q) { return __uint_as_float(q << 16); }
__device__ __forceinline__ float bfhi(u32 q) { return __uint_as_float(q & 0xffff0000u); }

// fence-free grid barrier (h traffic is agent-scope/L3-coherent; only vmcnt drain needed)
__device__ __forceinline__ void grid_barrier8(u32* leaf, u32* root, u32 rtarget, int g) {
    asm volatile("s_waitcnt vmcnt(0)" ::: "memory");
    __syncthreads();
    if (threadIdx.x == 0) {
        u32 old = __hip_atomic_fetch_add(&leaf[(g & 7) * 16], 1u,
                                         __ATOMIC_RELAXED, __HIP_MEMORY_SCOPE_AGENT);
        if ((old & 7u) == 7u)   // 8 WGs per leaf (64 WGs total)
            __hip_atomic_fetch_add(root, 1u, __ATOMIC_RELAXED, __HIP_MEMORY_SCOPE_AGENT);
        while (__hip_atomic_load(root, __ATOMIC_RELAXED, __HIP_MEMORY_SCOPE_AGENT) < rtarget)
            __builtin_amdgcn_s_sleep(2);
    }
    __syncthreads();
}
__device__ __forceinline__ void grid_barrier32(u32* leaf, u32* root, u32 rtarget, int g) {
    asm volatile("s_waitcnt vmcnt(0)" ::: "memory");
    __syncthreads();
    if (threadIdx.x == 0) {
        u32 old = __hip_atomic_fetch_add(&leaf[(g & 7) * 16], 1u,
                                         __ATOMIC_RELAXED, __HIP_MEMORY_SCOPE_AGENT);
        if ((old & 31u) == 31u)
            __hip_atomic_fetch_add(root, 1u, __ATOMIC_RELAXED, __HIP_MEMORY_SCOPE_AGENT);
        while (__hip_atomic_load(root, __ATOMIC_RELAXED, __HIP_MEMORY_SCOPE_AGENT) < rtarget)
            __builtin_amdgcn_s_sleep(2);
    }
    __syncthreads();
}

// ===================== PREPASS: ig = a @ Wih^T + bias (bf16 MFMA) =====================
// grid (32 g-pairs, 64 t-blocks), 192 threads (3 waves). Each wave owns 2 row-tiles
// (q = rt, rt+3) with Wih fragments register-stationary; B-frags (a) from global + cvt.
// Output layout: ig_u16[((t*64 + g)*32 + b)*48 + m]   (m: [0,16)=r,[16,32)=z,[32,48)=n)
__global__ __launch_bounds__(192, 2) void ig_prepass_mfma(
    const float* __restrict__ a, const float* __restrict__ Wih,
    const float* __restrict__ bias, char* __restrict__ igbase)
{
    const int gp   = blockIdx.x;          // g-pair: g = gp*2 + (q&1)
    const int t0   = blockIdx.y * 64;
    const int tid  = threadIdx.x;
    const int lane = tid & 63;
    const int rt   = tid >> 6;            // 0..2

    const int qA = rt, qB = rt + 3;

    short8 afragA[16], afragB[16];
    float biasA[4], biasB[4];
    {
        const float* wrA = &Wih[(size_t)((qA >> 1) * WW + gp * 32 + (qA & 1) * 16 + (lane & 15)) * PP + (lane >> 4) * 8];
        const float* wrB = &Wih[(size_t)((qB >> 1) * WW + gp * 32 + (qB & 1) * 16 + (lane & 15)) * PP + (lane >> 4) * 8];
        #pragma unroll
        for (int s = 0; s < 16; ++s) {
            float ta[8], tb[8];
            *(float4*)&ta[0] = *(const float4*)&wrA[s * 32];
            *(float4*)&ta[4] = *(const float4*)&wrA[s * 32 + 4];
            *(float4*)&tb[0] = *(const float4*)&wrB[s * 32];
            *(float4*)&tb[4] = *(const float4*)&wrB[s * 32 + 4];
            #pragma unroll
            for (int j = 0; j < 8; ++j) { afragA[s][j] = (short)bfround(ta[j]); afragB[s][j] = (short)bfround(tb[j]); }
        }
        #pragma unroll
        for (int r = 0; r < 4; ++r) {
            biasA[r] = bias[(qA >> 1) * WW + gp * 32 + (qA & 1) * 16 + (lane >> 4) * 4 + r];
            biasB[r] = bias[(qB >> 1) * WW + gp * 32 + (qB & 1) * 16 + (lane >> 4) * 4 + r];
        }
    }

    const int bcol = lane & 15;
    const int gA = gp * 2 + (qA & 1), gB = gp * 2 + (qB & 1);
    const int m0A = (qA >> 1) * 16 + (lane >> 4) * 4;
    const int m0B = (qB >> 1) * 16 + (lane >> 4) * 4;

    for (int ct = 0; ct < 128; ++ct) {
        const int tl = ct >> 1, bh = ct & 1;
        const int t  = t0 + tl;
        const int b  = bh * 16 + bcol;
        const float* ap = &a[((size_t)b * TT + t) * PP + (lane >> 4) * 8];
        f32x4 dA = {0.f, 0.f, 0.f, 0.f}, dB = {0.f, 0.f, 0.f, 0.f};
        #pragma unroll 4
        for (int s = 0; s < 16; ++s) {
            float4 lo = *(const float4*)&ap[s * 32];
            float4 hi = *(const float4*)&ap[s * 32 + 4];
            short8 bfv;
            bfv[0] = (short)((__float_as_uint(lo.x) + 0x8000u) >> 16);
            bfv[1] = (short)((__float_as_uint(lo.y) + 0x8000u) >> 16);
            bfv[2] = (short)((__float_as_uint(lo.z) + 0x8000u) >> 16);
            bfv[3] = (short)((__float_as_uint(lo.w) + 0x8000u) >> 16);
            bfv[4] = (short)((__float_as_uint(hi.x) + 0x8000u) >> 16);
            bfv[5] = (short)((__float_as_uint(hi.y) + 0x8000u) >> 16);
            bfv[6] = (short)((__float_as_uint(hi.z) + 0x8000u) >> 16);
            bfv[7] = (short)((__float_as_uint(hi.w) + 0x8000u) >> 16);
            dA = __builtin_amdgcn_mfma_f32_16x16x32_bf16(afragA[s], bfv, dA, 0, 0, 0);
            dB = __builtin_amdgcn_mfma_f32_16x16x32_bf16(afragB[s], bfv, dB, 0, 0, 0);
        }
        u32 loA = bfround(dA[0] + biasA[0]) | (bfround(dA[1] + biasA[1]) << 16);
        u32 hiA = bfround(dA[2] + biasA[2]) | (bfround(dA[3] + biasA[3]) << 16);
        u32 loB = bfround(dB[0] + biasB[0]) | (bfround(dB[1] + biasB[1]) << 16);
        u32 hiB = bfround(dB[2] + biasB[2]) | (bfround(dB[3] + biasB[3]) << 16);
        *(u64*)(igbase + (((size_t)t * 64 + gA) * 1536 + (size_t)b * 48 + m0A) * 2) = (u64)loA | ((u64)hiA << 32);
        *(u64*)(igbase + (((size_t)t * 64 + gB) * 1536 + (size_t)b * 48 + m0B) * 2) = (u64)loB | ((u64)hiB << 32);
    }
}

// ===================== SCAN: MFMA recurrence, 64 WGs x 16 hidden =====================
// h exchange layout (unchanged math): u64 idx = k8*64 + 2*b + p holds h[8*k8+4*p .. +3][b]
// => uint4 idx (k8*32+b) = h[8k8..8k8+7][b] = exactly one MFMA B-fragment per lane.
__global__ __launch_bounds__(768, 3) void gru_scan_mfma(
    const float* __restrict__ h0, const float* __restrict__ Whh,
    const float* __restrict__ bias_n, const float* __restrict__ Wout,
    const float* __restrict__ bout, const char* __restrict__ igbase,
    float* __restrict__ out, u64* __restrict__ hbufA, u64* __restrict__ hbufB,
    u32* __restrict__ leaf, u32* __restrict__ root)
{
    __shared__ __align__(16) u64 sh[8192];          // 64 KB staged h (bf16)
    __shared__ float sPreH[2][48][33];              // hh-dot partials (k-halves)
    __shared__ float sOutP[4][16][17];              // p3 partials (k-quarters)
    __shared__ __align__(8) u64 sIgRaw[384];        // ig slice (48x32 bf16)
    __shared__ unsigned short sHnew[16][32];        // new h (bf16)

    const int g    = blockIdx.x;                    // 0..63, owns w = g*16..g*16+15
    const int tid  = threadIdx.x;
    const int lane = tid & 63;
    const int wid  = tid >> 6;                      // 0..11
    const int rt   = wid >> 2;                      // row-tile 0..2 (gate)
    const int bt   = (wid >> 1) & 1;                // b-tile
    const int kh   = wid & 1;                       // k-half

    // ---- loop-invariant A-fragments: Whh (16 kslices of this wave's k-half) ----
    short8 afrag[16];
    {
        const float* wr = &Whh[(size_t)(rt * WW + g * 16 + (lane & 15)) * WW + kh * 512 + (lane >> 4) * 8];
        #pragma unroll
        for (int s = 0; s < 16; ++s) {
            float tmp[8];
            *(float4*)&tmp[0] = *(const float4*)&wr[s * 32];
            *(float4*)&tmp[4] = *(const float4*)&wr[s * 32 + 4];
            #pragma unroll
            for (int j = 0; j < 8; ++j) afrag[s][j] = (short)bfround(tmp[j]);
        }
    }
    // ---- p3 A-fragments: Wout (waves 0-3, one k-quarter each) ----
    const int p0  = (g >> 1) * 16;                  // p-tile base
    const int pb0 = (g & 1) * 16;                   // b-tile base for p3
    short8 pfrag[8];
    if (wid < 4) {
        const float* wr = &Wout[(size_t)(p0 + (lane & 15)) * WW + (lane >> 4) * 8];
        #pragma unroll
        for (int s = 0; s < 8; ++s) {
            const int k0 = (wid * 8 + s) * 32;
            float tmp[8];
            *(float4*)&tmp[0] = *(const float4*)&wr[k0];
            *(float4*)&tmp[4] = *(const float4*)&wr[k0 + 4];
            #pragma unroll
            for (int j = 0; j < 8; ++j) pfrag[s][j] = (short)bfround(tmp[j]);
        }
    }

    // ---- gate-thread state (tid 256..767 -> (wl, b)) ----
    float h_own = 0.f, bnv = 0.f;
    int gwl = 0, gb = 0;
    if (tid >= 256) {
        const int idx = tid - 256;
        gwl = idx >> 5; gb = idx & 31;
        h_own = h0[g * 16 + gwl];
        bnv   = bias_n[g * 16 + gwl];
    }
    float boutp = 0.f;
    if (tid < 256) boutp = bout[p0 + (tid & 15)];

    // ---- h0 exchange init (packers tid<128) ----
    if (tid < 128) {
        const int wq = tid >> 5, b = tid & 31;
        const int wbase = g * 16 + wq * 4;
        u32 lo = bfround(h0[wbase]) | (bfround(h0[wbase + 1]) << 16);
        u32 hi = bfround(h0[wbase + 2]) | (bfround(h0[wbase + 3]) << 16);
        const int idx = (2 * g + (wq >> 1)) * 64 + 2 * b + (wq & 1);
        __hip_atomic_store(&hbufA[idx], (u64)lo | ((u64)hi << 32),
                           __ATOMIC_RELAXED, __HIP_MEMORY_SCOPE_AGENT);
    }

    u32 rtarget = 8;
    grid_barrier8(leaf, root, rtarget, g);

    u64* hcur = hbufA;
    u64* hnxt = hbufB;
    const short8* shf = (const short8*)sh;
    const int foff = (lane >> 4) * 32 + bt * 16 + (lane & 15);   // hh B-frag offset
    const int poff = (lane >> 4) * 32 + pb0 + (lane & 15);       // p3 B-frag offset

    for (int t = TT - 1; t >= 0; --t) {
        // ---- stage h_{t+1} + ig_t ----
        u64 r0, r1, r2, r3, r4, r5, r6, r7, r8, r9, r10 = 0;
        #define LDH(J) __hip_atomic_load(&hcur[tid + (J) * 768], __ATOMIC_RELAXED, __HIP_MEMORY_SCOPE_AGENT)
        r0 = LDH(0); r1 = LDH(1); r2 = LDH(2); r3 = LDH(3); r4 = LDH(4);
        r5 = LDH(5); r6 = LDH(6); r7 = LDH(7); r8 = LDH(8); r9 = LDH(9);
        if (tid < 512) r10 = LDH(10);
        #undef LDH
        u64 igr = 0;
        if (tid < 384) igr = *(const u64*)(igbase + ((size_t)t * 64 + g) * 3072 + tid * 8);

        sh[tid] = r0;            sh[tid + 768] = r1;   sh[tid + 1536] = r2;
        sh[tid + 2304] = r3;     sh[tid + 3072] = r4;  sh[tid + 3840] = r5;
        sh[tid + 4608] = r6;     sh[tid + 5376] = r7;  sh[tid + 6144] = r8;
        sh[tid + 6912] = r9;
        if (tid < 512) sh[tid + 7680] = r10;
        if (tid < 384) sIgRaw[tid] = igr;
        __syncthreads();

        // ---- hh-dot MFMA: 16 kslices, 2 interleaved accumulators ----
        {
            f32x4 c0 = {0.f, 0.f, 0.f, 0.f}, c1 = {0.f, 0.f, 0.f, 0.f};
            #pragma unroll
            for (int s = 0; s < 16; s += 2) {
                const int ss = kh * 16 + s;
                short8 b0f = shf[ss * 128 + foff];
                short8 b1f = shf[(ss + 1) * 128 + foff];
                c0 = __builtin_amdgcn_mfma_f32_16x16x32_bf16(afrag[s],     b0f, c0, 0, 0, 0);
                c1 = __builtin_amdgcn_mfma_f32_16x16x32_bf16(afrag[s + 1], b1f, c1, 0, 0, 0);
            }
            c0 = c0 + c1;
            #pragma unroll
            for (int r = 0; r < 4; ++r)
                sPreH[kh][rt * 16 + (lane >> 4) * 4 + r][bt * 16 + (lane & 15)] = c0[r];
        }
        // ---- p3 MFMA for h_{t+1} (waves 0-3) ----
        if (wid < 4 && t < TT - 1) {
            f32x4 d = {0.f, 0.f, 0.f, 0.f};
            #pragma unroll
            for (int s = 0; s < 8; ++s) {
                const int ss = wid * 8 + s;
                short8 bf = shf[ss * 128 + poff];
                d = __builtin_amdgcn_mfma_f32_16x16x32_bf16(pfrag[s], bf, d, 0, 0, 0);
            }
            #pragma unroll
            for (int r = 0; r < 4; ++r)
                sOutP[wid][(lane >> 4) * 4 + r][lane & 15] = d[r];
        }
        __syncthreads();

        // ---- gates (tid>=256) / out store (tid<256) ----
        if (tid >= 256) {
            const unsigned short* sIgU = (const unsigned short*)sIgRaw;
            const float ig_r = bf2f(sIgU[gb * 48 + gwl]);
            const float ig_z = bf2f(sIgU[gb * 48 + 16 + gwl]);
            const float ig_n = bf2f(sIgU[gb * 48 + 32 + gwl]);
            const float hg_r = sPreH[0][gwl][gb]      + sPreH[1][gwl][gb];
            const float hg_z = sPreH[0][16 + gwl][gb] + sPreH[1][16 + gwl][gb];
            const float hg_n = sPreH[0][32 + gwl][gb] + sPreH[1][32 + gwl][gb];
            const float rr = 1.f / (1.f + __expf(-(ig_r + hg_r)));
            const float zz = 1.f / (1.f + __expf(-(ig_z + hg_z)));
            const float nn = tanhf(ig_n + rr * (hg_n + bnv));
            h_own = nn + zz * (h_own - nn);
            sHnew[gwl][gb] = (unsigned short)bfround(h_own);
        } else if (t < TT - 1) {
            const int p = tid & 15, b = tid >> 4;
            const float s_ = boutp + sOutP[0][p][b] + sOutP[1][p][b]
                                   + sOutP[2][p][b] + sOutP[3][p][b];
            out[((size_t)(pb0 + b) * TT + (t + 1)) * PP + p0 + p] = s_;
        }
        __syncthreads();

        // ---- pack + exchange-store new h ----
        if (tid < 128) {
            const int wq = tid >> 5, b = tid & 31;
            u32 lo = (u32)sHnew[wq * 4][b]     | ((u32)sHnew[wq * 4 + 1][b] << 16);
            u32 hi = (u32)sHnew[wq * 4 + 2][b] | ((u32)sHnew[wq * 4 + 3][b] << 16);
            const int idx = (2 * g + (wq >> 1)) * 64 + 2 * b + (wq & 1);
            __hip_atomic_store(&hnxt[idx], (u64)lo | ((u64)hi << 32),
                               __ATOMIC_RELAXED, __HIP_MEMORY_SCOPE_AGENT);
        }

        rtarget += 8;
        grid_barrier8(leaf, root, rtarget, g);
        u64* tmp = hcur; hcur = hnxt; hnxt = tmp;
    }

    // ---- epilogue: project h_0 -> out[:,0,:] ----
    {
        u64 r0, r1, r2, r3, r4, r5, r6, r7, r8, r9, r10 = 0;
        #define LDH(J) __hip_atomic_load(&hcur[tid + (J) * 768], __ATOMIC_RELAXED, __HIP_MEMORY_SCOPE_AGENT)
        r0 = LDH(0); r1 = LDH(1); r2 = LDH(2); r3 = LDH(3); r4 = LDH(4);
        r5 = LDH(5); r6 = LDH(6); r7 = LDH(7); r8 = LDH(8); r9 = LDH(9);
        if (tid < 512) r10 = LDH(10);
        #undef LDH
        sh[tid] = r0;            sh[tid + 768] = r1;   sh[tid + 1536] = r2;
        sh[tid + 2304] = r3;     sh[tid + 3072] = r4;  sh[tid + 3840] = r5;
        sh[tid + 4608] = r6;     sh[tid + 5376] = r7;  sh[tid + 6144] = r8;
        sh[tid + 6912] = r9;
        if (tid < 512) sh[tid + 7680] = r10;
        __syncthreads();
        if (wid < 4) {
            f32x4 d = {0.f, 0.f, 0.f, 0.f};
            #pragma unroll
            for (int s = 0; s < 8; ++s) {
                const int ss = wid * 8 + s;
                short8 bf = shf[ss * 128 + poff];
                d = __builtin_amdgcn_mfma_f32_16x16x32_bf16(pfrag[s], bf, d, 0, 0, 0);
            }
            #pragma unroll
            for (int r = 0; r < 4; ++r)
                sOutP[wid][(lane >> 4) * 4 + r][lane & 15] = d[r];
        }
        __syncthreads();
        if (tid < 256) {
            const int p = tid & 15, b = tid >> 4;
            const float s_ = boutp + sOutP[0][p][b] + sOutP[1][p][b]
                                   + sOutP[2][p][b] + sOutP[3][p][b];
            out[((size_t)(pb0 + b) * TT) * PP + p0 + p] = s_;
        }
    }
}

// ===================== FALLBACK (proven R3 kernel, 256 WGs) =====================
__global__ __launch_bounds__(768, 1) void gru_scan_fb(
    const float* __restrict__ a, const float* __restrict__ h0,
    const float* __restrict__ Wih, const float* __restrict__ Whh,
    const float* __restrict__ bias, const float* __restrict__ bias_n,
    const float* __restrict__ Wout, const float* __restrict__ bout,
    float* __restrict__ out, u64* __restrict__ hbufA, u64* __restrict__ hbufB,
    u32* __restrict__ leaf, u32* __restrict__ root)
{
    __shared__ float sWhh[12][WW];
    __shared__ __align__(16) u64 sh[8192];
    __shared__ float sPreH[2][12][BB];
    __shared__ float sIg[2][2][12][BB];
    __shared__ float sOutPart[12][64];

    const int g   = blockIdx.x;
    const int tid = threadIdx.x;
    const int w0  = g * 4;

    for (int i = tid; i < 12 * (WW / 4); i += 768) {
        int row_ = i / (WW / 4);
        int k4_  = i - row_ * (WW / 4);
        int gr   = (row_ >> 2) * WW + w0 + (row_ & 3);
        *(float4*)&sWhh[row_][k4_ * 4] = *(const float4*)&Whh[(size_t)gr * WW + k4_ * 4];
    }
    const int  half = (tid >= 384) ? 1 : 0;
    const int  sub  = tid - half * 384;
    const int  b1   = sub & 31;
    const int  row  = sub >> 5;
    const int  grow = (row >> 2) * WW + w0 + (row & 3);
    const float biasv = (half == 0) ? bias[grow] : 0.0f;

    float ho0 = 0.f, ho1 = 0.f, ho2 = 0.f, ho3 = 0.f;
    float bn0 = 0.f, bn1 = 0.f, bn2 = 0.f, bn3 = 0.f;
    if (tid < 32) {
        ho0 = h0[w0 + 0]; ho1 = h0[w0 + 1]; ho2 = h0[w0 + 2]; ho3 = h0[w0 + 3];
        bn0 = bias_n[w0 + 0]; bn1 = bias_n[w0 + 1]; bn2 = bias_n[w0 + 2]; bn3 = bias_n[w0 + 3];
        u32 lo = bfround(ho0) | (bfround(ho1) << 16);
        u32 hi = bfround(ho2) | (bfround(ho3) << 16);
        __hip_atomic_store(&hbufA[g * 32 + tid], (u64)lo | ((u64)hi << 32),
                           __ATOMIC_RELAXED, __HIP_MEMORY_SCOPE_AGENT);
    }
    const int  p0  = (g & 31) * 16;
    const int  b0  = (g >> 5) * 4;
    const int  o   = tid & 63;
    const int  c   = tid >> 6;
    const int  p3p = p0 + (o & 15);
    const int  p3b = b0 + (o >> 4);
    const float boutv = bout[p3p];

    auto ihdot = [&](int t_, int pbuf) {
        const float4* __restrict__ arow = (const float4*)&a[((size_t)b1 * TT + t_) * PP];
        const float4* __restrict__ wrow = (const float4*)&Wih[(size_t)grow * PP];
        const int p40 = half * 64;
        float4 acc = {0.f, 0.f, 0.f, 0.f};
        #pragma unroll 8
        for (int p4 = 0; p4 < 64; ++p4) {
            float4 av = arow[p40 + p4];
            float4 wv = wrow[p40 + p4];
            acc.x += av.x * wv.x; acc.y += av.y * wv.y;
            acc.z += av.z * wv.z; acc.w += av.w * wv.w;
        }
        sIg[pbuf][half][row][b1] = (acc.x + acc.y) + (acc.z + acc.w) + biasv;
    };
    auto p3partials = [&]() {
        const float4* __restrict__ wrow = (const float4*)&Wout[(size_t)p3p * WW];
        float4 acc = {0.f, 0.f, 0.f, 0.f};
        for (int k4 = c; k4 < WW / 4; k4 += 12) {
            u64 pk = sh[k4 * 32 + p3b];
            float4 wv = wrow[k4];
            acc.x += bflo((u32)pk) * wv.x;
            acc.y += bfhi((u32)pk) * wv.y;
            acc.z += bflo((u32)(pk >> 32)) * wv.z;
            acc.w += bfhi((u32)(pk >> 32)) * wv.w;
        }
        sOutPart[c][o] = (acc.x + acc.y) + (acc.z + acc.w);
    };

    ihdot(TT - 1, 1);
    u32 rtarget = 8;
    grid_barrier32(leaf, root, rtarget, g);
    u64* hcur = hbufA;
    u64* hnxt = hbufB;

    for (int t = TT - 1; t >= 0; --t) {
        const int par = t & 1;
        u64 r0, r1, r2, r3, r4, r5, r6, r7, r8, r9, r10 = 0;
        #define LDH(J) __hip_atomic_load(&hcur[tid + (J) * 768], __ATOMIC_RELAXED, __HIP_MEMORY_SCOPE_AGENT)
        r0 = LDH(0); r1 = LDH(1); r2 = LDH(2); r3 = LDH(3); r4 = LDH(4);
        r5 = LDH(5); r6 = LDH(6); r7 = LDH(7); r8 = LDH(8); r9 = LDH(9);
        if (tid < 512) r10 = LDH(10);
        #undef LDH
        if (t > 0) ihdot(t - 1, par ^ 1);
        sh[tid] = r0;          sh[tid + 768] = r1;   sh[tid + 1536] = r2;
        sh[tid + 2304] = r3;   sh[tid + 3072] = r4;  sh[tid + 3840] = r5;
        sh[tid + 4608] = r6;   sh[tid + 5376] = r7;  sh[tid + 6144] = r8;
        sh[tid + 6912] = r9;
        if (tid < 512) sh[tid + 7680] = r10;
        __syncthreads();
        {
            const int k40 = half * 128;
            float4 acc = {0.f, 0.f, 0.f, 0.f};
            #pragma unroll 4
            for (int k4 = 0; k4 < 128; ++k4) {
                u64 pk = sh[(k40 + k4) * 32 + b1];
                float4 wv = *(const float4*)&sWhh[row][(k40 + k4) * 4];
                acc.x += bflo((u32)pk) * wv.x;
                acc.y += bfhi((u32)pk) * wv.y;
                acc.z += bflo((u32)(pk >> 32)) * wv.z;
                acc.w += bfhi((u32)(pk >> 32)) * wv.w;
            }
            sPreH[half][row][b1] = (acc.x + acc.y) + (acc.z + acc.w);
        }
        if (t < TT - 1) p3partials();
        __syncthreads();
        if (tid < 32) {
            const int b = tid;
            float hn0, hn1, hn2, hn3;
            {
                float rr = 1.f / (1.f + __expf(-(sIg[par][0][0][b] + sIg[par][1][0][b] + sPreH[0][0][b] + sPreH[1][0][b])));
                float zz = 1.f / (1.f + __expf(-(sIg[par][0][4][b] + sIg[par][1][4][b] + sPreH[0][4][b] + sPreH[1][4][b])));
                float nn = tanhf(sIg[par][0][8][b] + sIg[par][1][8][b] + rr * (sPreH[0][8][b] + sPreH[1][8][b] + bn0));
                hn0 = nn + zz * (ho0 - nn); ho0 = hn0;
            }
            {
                float rr = 1.f / (1.f + __expf(-(sIg[par][0][1][b] + sIg[par][1][1][b] + sPreH[0][1][b] + sPreH[1][1][b])));
                float zz = 1.f / (1.f + __expf(-(sIg[par][0][5][b] + sIg[par][1][5][b] + sPreH[0][5][b] + sPreH[1][5][b])));
                float nn = tanhf(sIg[par][0][9][b] + sIg[par][1][9][b] + rr * (sPreH[0][9][b] + sPreH[1][9][b] + bn1));
                hn1 = nn + zz * (ho1 - nn); ho1 = hn1;
            }
            {
                float rr = 1.f / (1.f + __expf(-(sIg[par][0][2][b] + sIg[par][1][2][b] + sPreH[0][2][b] + sPreH[1][2][b])));
                float zz = 1.f / (1.f + __expf(-(sIg[par][0][6][b] + sIg[par][1][6][b] + sPreH[0][6][b] + sPreH[1][6][b])));
                float nn = tanhf(sIg[par][0][10][b] + sIg[par][1][10][b] + rr * (sPreH[0][10][b] + sPreH[1][10][b] + bn2));
                hn2 = nn + zz * (ho2 - nn); ho2 = hn2;
            }
            {
                float rr = 1.f / (1.f + __expf(-(sIg[par][0][3][b] + sIg[par][1][3][b] + sPreH[0][3][b] + sPreH[1][3][b])));
                float zz = 1.f / (1.f + __expf(-(sIg[par][0][7][b] + sIg[par][1][7][b] + sPreH[0][7][b] + sPreH[1][7][b])));
                float nn = tanhf(sIg[par][0][11][b] + sIg[par][1][11][b] + rr * (sPreH[0][11][b] + sPreH[1][11][b] + bn3));
                hn3 = nn + zz * (ho3 - nn); ho3 = hn3;
            }
            u32 lo = bfround(hn0) | (bfround(hn1) << 16);
            u32 hi = bfround(hn2) | (bfround(hn3) << 16);
            __hip_atomic_store(&hnxt[g * 32 + tid], (u64)lo | ((u64)hi << 32),
                               __ATOMIC_RELAXED, __HIP_MEMORY_SCOPE_AGENT);
        }
        if (t < TT - 1 && tid < 64) {
            float s_ = boutv;
            #pragma unroll
            for (int cc = 0; cc < 12; ++cc) s_ += sOutPart[cc][o];
            out[((size_t)p3b * TT + (t + 1)) * PP + p3p] = s_;
        }
        rtarget += 8;
        grid_barrier32(leaf, root, rtarget, g);
        u64* tmp = hcur; hcur = hnxt; hnxt = tmp;
    }
    {
        u64 r0, r1, r2, r3, r4, r5, r6, r7, r8, r9, r10 = 0;
        #define LDH(J) __hip_atomic_load(&hcur[tid + (J) * 768], __ATOMIC_RELAXED, __HIP_MEMORY_SCOPE_AGENT)
        r0 = LDH(0); r1 = LDH(1); r2 = LDH(2); r3 = LDH(3); r4 = LDH(4);
        r5 = LDH(5); r6 = LDH(6); r7 = LDH(7); r8 = LDH(8); r9 = LDH(9);
        if (tid < 512) r10 = LDH(10);
        #undef LDH
        sh[tid] = r0;          sh[tid + 768] = r1;   sh[tid + 1536] = r2;
        sh[tid + 2304] = r3;   sh[tid + 3072] = r4;  sh[tid + 3840] = r5;
        sh[tid + 4608] = r6;   sh[tid + 5376] = r7;  sh[tid + 6144] = r8;
        sh[tid + 6912] = r9;
        if (tid < 512) sh[tid + 7680] = r10;
        __syncthreads();
        p3partials();
        __syncthreads();
        if (tid < 64) {
            float s_ = boutv;
            #pragma unroll
            for (int cc = 0; cc < 12; ++cc) s_ += sOutPart[cc][o];
            out[((size_t)p3b * TT) * PP + p3p] = s_;
        }
    }
}

extern "C" void kernel_launch(void* const* d_in, const int* in_sizes, int n_in,
                              void* d_out, int out_size, void* d_ws, size_t ws_size,
                              hipStream_t stream) {
    const float* a      = (const float*)d_in[0];
    const float* h0     = (const float*)d_in[1];
    const float* Wih    = (const float*)d_in[2];
    const float* Whh    = (const float*)d_in[3];
    const float* bias   = (const float*)d_in[4];
    const float* bias_n = (const float*)d_in[5];
    const float* Wout   = (const float*)d_in[6];
    const float* bout   = (const float*)d_in[7];
    float* out = (float*)d_out;

    const size_t IG_BYTES = (size_t)TT * 64 * 3072;          // 805,306,368
    const size_t NEED     = IG_BYTES + 2 * 65536 + 1024;

    if (ws_size >= NEED) {
        char* igbase = (char*)d_ws;
        u64*  hA   = (u64*)((char*)d_ws + IG_BYTES);
        u64*  hB   = hA + 8192;
        u32*  leaf = (u32*)((char*)d_ws + IG_BYTES + 2 * 65536);
        u32*  root = leaf + 8 * 16;
        hipMemsetAsync(leaf, 0, 1024, stream);
        hipLaunchKernelGGL(ig_prepass_mfma, dim3(32, 64), dim3(192), 0, stream,
                           a, Wih, bias, igbase);
        void* args[] = {(void*)&h0, (void*)&Whh, (void*)&bias_n, (void*)&Wout,
                        (void*)&bout, (void*)&igbase, (void*)&out,
                        (void*)&hA, (void*)&hB, (void*)&leaf, (void*)&root};
        hipLaunchCooperativeKernel((void*)gru_scan_mfma, dim3(64), dim3(768),
                                   args, 0, stream);
    } else {
        u64* hA   = (u64*)d_ws;
        u64* hB   = hA + 8192;
        u32* leaf = (u32*)((char*)d_ws + 2 * 65536);
        u32* root = leaf + 8 * 16;
        hipMemsetAsync(leaf, 0, 1024, stream);
        void* args[] = {(void*)&a, (void*)&h0, (void*)&Wih, (void*)&Whh,
                        (void*)&bias, (void*)&bias_n, (void*)&Wout, (void*)&bout,
                        (void*)&out, (void*)&hA, (void*)&hB, (void*)&leaf, (void*)&root};
        hipLaunchCooperativeKernel((void*)gru_scan_fb, dim3(256), dim3(768),
                                   args, 0, stream);
    }
}